// Round 1
// baseline (59.296 us; speedup 1.0000x reference)
//
#include <hip/hip_runtime.h>

// ConstrainedAttentionModel: B=8, T=2048, V=8192, K=3.
// scores[b,t] = sum_{i,j, t>=j} params[i][j] * [x[b,t-j] == x[b,T-1-i]]
// scores[b,T-1] = -1e9 ; attn = softmax_t(scores) ; out[b,v] = sum_{t:x[b,t]==v} attn[b,t]

constexpr int T = 2048;
constexpr int V = 8192;
constexpr int BLOCK = 1024;
constexpr int PER = T / BLOCK;        // 2 positions per thread
constexpr int NWAVE = BLOCK / 64;     // 16 waves

__global__ __launch_bounds__(BLOCK)
void ca_kernel(const int* __restrict__ x, const float* __restrict__ params,
               float* __restrict__ out) {
    const int b = blockIdx.x;
    const int tid = threadIdx.x;
    const int* xb = x + b * T;
    float* ob = out + b * V;

    __shared__ int s_x[T];
    __shared__ float s_red[NWAVE];

    // Stage tokens (coalesced), zero the output row (re-poisoned each launch).
    #pragma unroll
    for (int k = 0; k < PER; ++k) s_x[tid + k * BLOCK] = xb[tid + k * BLOCK];

    float4* ob4 = reinterpret_cast<float4*>(ob);
    #pragma unroll
    for (int k = 0; k < (V / 4) / BLOCK; ++k)
        ob4[tid + k * BLOCK] = make_float4(0.f, 0.f, 0.f, 0.f);

    // params[i][j], i = query index (x[T-1-i]), j = window offset (x[t-j])
    const float p00 = params[0], p01 = params[1], p02 = params[2];
    const float p10 = params[3], p11 = params[4], p12 = params[5];
    const float p20 = params[6], p21 = params[7], p22 = params[8];

    __syncthreads();
    const int q0 = s_x[T - 1], q1 = s_x[T - 2], q2 = s_x[T - 3];

    // --- scores (kept in registers; each thread owns its own t's) ---
    float sc[PER];
    float lmax = -3.0e38f;
    #pragma unroll
    for (int k = 0; k < PER; ++k) {
        const int t = tid + k * BLOCK;
        float s = 0.f;
        const int t0 = s_x[t];                 // j = 0
        if (t0 == q0) s += p00;
        if (t0 == q1) s += p10;
        if (t0 == q2) s += p20;
        if (t >= 1) {                          // j = 1
            const int t1 = s_x[t - 1];
            if (t1 == q0) s += p01;
            if (t1 == q1) s += p11;
            if (t1 == q2) s += p21;
        }
        if (t >= 2) {                          // j = 2
            const int t2 = s_x[t - 2];
            if (t2 == q0) s += p02;
            if (t2 == q1) s += p12;
            if (t2 == q2) s += p22;
        }
        if (t == T - 1) s = -1.0e9f;           // masked position
        sc[k] = s;
        lmax = fmaxf(lmax, s);
    }

    // --- block max ---
    #pragma unroll
    for (int off = 32; off >= 1; off >>= 1)
        lmax = fmaxf(lmax, __shfl_down(lmax, off, 64));
    const int wave = tid >> 6, lane = tid & 63;
    if (lane == 0) s_red[wave] = lmax;
    __syncthreads();
    float M = s_red[0];
    #pragma unroll
    for (int w = 1; w < NWAVE; ++w) M = fmaxf(M, s_red[w]);
    __syncthreads();

    // --- sum of exp ---
    float e[PER];
    float lsum = 0.f;
    #pragma unroll
    for (int k = 0; k < PER; ++k) { e[k] = expf(sc[k] - M); lsum += e[k]; }
    #pragma unroll
    for (int off = 32; off >= 1; off >>= 1)
        lsum += __shfl_down(lsum, off, 64);
    if (lane == 0) s_red[wave] = lsum;
    __syncthreads();
    float S = 0.f;
    #pragma unroll
    for (int w = 0; w < NWAVE; ++w) S += s_red[w];
    const float inv = 1.f / S;

    // --- scatter attn into output row (duplicates rare -> atomics cheap) ---
    #pragma unroll
    for (int k = 0; k < PER; ++k) {
        const int t = tid + k * BLOCK;
        atomicAdd(&ob[s_x[t]], e[k] * inv);
    }
}

extern "C" void kernel_launch(void* const* d_in, const int* in_sizes, int n_in,
                              void* d_out, int out_size, void* d_ws, size_t ws_size,
                              hipStream_t stream) {
    const int* x = (const int*)d_in[0];          // (B, T) int32
    const float* params = (const float*)d_in[1]; // (3, 3) fp32
    float* out = (float*)d_out;                  // (B, V) fp32
    const int B = in_sizes[0] / T;               // 8
    ca_kernel<<<B, BLOCK, 0, stream>>>(x, params, out);
}

// Round 2
// 58.358 us; speedup vs baseline: 1.0161x; 1.0161x over previous
//
#include <hip/hip_runtime.h>

// ConstrainedAttentionModel: B=8, T=2048, V=8192, K=3.
// scores[b,t] = sum_{i,j, t>=j} params[i][j] * [x[b,t-j] == x[b,T-1-i]]
// scores[b,T-1] = -1e9 ; attn = softmax_t(scores) ; out[b,v] = sum_{t:x[b,t]==v} attn[b,t]
//
// R1 notes: bench dur is dominated by harness ws-poison fill (39 us, 268 MB).
// This revision minimizes our kernel's share: output row accumulated in LDS
// (no global zero / no global atomics), no max-pass softmax (scores bounded,
// masked -1e9 underflows expf to exact 0), 256-thread blocks (4 waves, cheap
// barriers), 3 barriers total.

constexpr int T = 2048;
constexpr int V = 8192;
constexpr int BLOCK = 256;
constexpr int PER = T / BLOCK;        // 8 positions per thread
constexpr int NWAVE = BLOCK / 64;     // 4 waves

__global__ __launch_bounds__(BLOCK)
void ca_kernel(const int* __restrict__ x, const float* __restrict__ params,
               float* __restrict__ out) {
    const int b = blockIdx.x;
    const int tid = threadIdx.x;

    __shared__ int   s_x[T];        // 8 KB
    __shared__ float s_acc[V];      // 32 KB
    __shared__ float s_red[NWAVE];

    // Stage tokens (int4-vectorized) and zero the LDS accumulator row.
    {
        const int4* xb4 = reinterpret_cast<const int4*>(x + b * T);
        int4* sx4 = reinterpret_cast<int4*>(s_x);
        #pragma unroll
        for (int k = 0; k < (T / 4) / BLOCK; ++k)        // 2 iters
            sx4[tid + k * BLOCK] = xb4[tid + k * BLOCK];

        float4* sa4 = reinterpret_cast<float4*>(s_acc);
        const float4 z = make_float4(0.f, 0.f, 0.f, 0.f);
        #pragma unroll
        for (int k = 0; k < (V / 4) / BLOCK; ++k)        // 8 iters
            sa4[tid + k * BLOCK] = z;
    }

    // params[i][j], i = query index (x[T-1-i]), j = window offset (x[t-j])
    const float p00 = params[0], p01 = params[1], p02 = params[2];
    const float p10 = params[3], p11 = params[4], p12 = params[5];
    const float p20 = params[6], p21 = params[7], p22 = params[8];

    __syncthreads();                                     // barrier 1
    const int q0 = s_x[T - 1], q1 = s_x[T - 2], q2 = s_x[T - 3];

    // --- scores + exp (no max-shift: |s| <= 9*max|param| << 80, masked -> 0) ---
    float e[PER];
    float lsum = 0.f;
    #pragma unroll
    for (int k = 0; k < PER; ++k) {
        const int t = tid + k * BLOCK;
        float s = 0.f;
        const int t0 = s_x[t];                 // j = 0
        if (t0 == q0) s += p00;
        if (t0 == q1) s += p10;
        if (t0 == q2) s += p20;
        if (t >= 1) {                          // j = 1
            const int t1 = s_x[t - 1];
            if (t1 == q0) s += p01;
            if (t1 == q1) s += p11;
            if (t1 == q2) s += p21;
        }
        if (t >= 2) {                          // j = 2
            const int t2 = s_x[t - 2];
            if (t2 == q0) s += p02;
            if (t2 == q1) s += p12;
            if (t2 == q2) s += p22;
        }
        if (t == T - 1) s = -1.0e9f;           // masked -> expf underflows to 0
        e[k] = expf(s);
        lsum += e[k];
    }

    // --- block sum ---
    #pragma unroll
    for (int off = 32; off >= 1; off >>= 1)
        lsum += __shfl_down(lsum, off, 64);
    const int wave = tid >> 6, lane = tid & 63;
    if (lane == 0) s_red[wave] = lsum;
    __syncthreads();                                     // barrier 2
    float S = 0.f;
    #pragma unroll
    for (int w = 0; w < NWAVE; ++w) S += s_red[w];
    const float inv = 1.f / S;

    // --- scatter attn into the LDS row (ds_add_f32; dup tokens rare) ---
    #pragma unroll
    for (int k = 0; k < PER; ++k) {
        const int t = tid + k * BLOCK;
        atomicAdd(&s_acc[s_x[t]], e[k] * inv);
    }
    __syncthreads();                                     // barrier 3

    // --- coalesced row store ---
    float4* ob4 = reinterpret_cast<float4*>(out + b * V);
    const float4* sa4 = reinterpret_cast<const float4*>(s_acc);
    #pragma unroll
    for (int k = 0; k < (V / 4) / BLOCK; ++k)            // 8 iters
        ob4[tid + k * BLOCK] = sa4[tid + k * BLOCK];
}

extern "C" void kernel_launch(void* const* d_in, const int* in_sizes, int n_in,
                              void* d_out, int out_size, void* d_ws, size_t ws_size,
                              hipStream_t stream) {
    const int* x = (const int*)d_in[0];          // (B, T) int32
    const float* params = (const float*)d_in[1]; // (3, 3) fp32
    float* out = (float*)d_out;                  // (B, V) fp32
    const int B = in_sizes[0] / T;               // 8
    ca_kernel<<<B, BLOCK, 0, stream>>>(x, params, out);
}